// Round 1
// baseline (695.295 us; speedup 1.0000x reference)
//
#include <hip/hip_runtime.h>

// SparseToDense: scatter [N, C] f32 features at flat (b,z,y,x) indices into
// dense [B, C, S, S, S] f32 output (channels-first).
// Fixed problem shape: N=262144, C=64, S=64, B=8.
//   S^3 = 2^18 = 262144 cells/batch, NCELL = B*S^3 = 2,097,152
//   out_size = B*C*S^3 = 134,217,728 floats (512 MiB)
//
// Strategy: invert the scatter into a gather so the 512 MiB output is written
// exactly once, fully coalesced (float4), with zero-fill fused in.
//   Phase 1: head[cell] = -1  (8 MiB table in d_ws)
//   Phase 2: linked lists via atomicExch: next[n] = atomicExch(&head[idx[n]], n)
//   Phase 3: output-ordered emit: each thread produces 4 consecutive spatial
//            positions of one (b, c) plane; traverses the (usually empty or
//            1-element) list per cell, gathers features[n*C + c], writes float4.
// head (8 MiB) + next (1 MiB) stay cache-resident; features (64 MiB) fits L3.

#define C_CH      64
#define LOG_C     6
#define LOG_S3    18
#define S3        (1 << LOG_S3)           // 262144
#define NCELL     (8 * S3)                // 2,097,152
#define OUT_ELEMS (8LL * C_CH * S3)       // 134,217,728

__global__ void init_head_kernel(int* __restrict__ head) {
    int i = blockIdx.x * blockDim.x + threadIdx.x;   // NCELL/4 threads
    ((int4*)head)[i] = make_int4(-1, -1, -1, -1);
}

__global__ void build_lists_kernel(const int* __restrict__ idx,
                                   int* __restrict__ head,
                                   int* __restrict__ nxt, int n) {
    int i = blockIdx.x * blockDim.x + threadIdx.x;
    if (i < n) {
        int cell = idx[i];
        nxt[i] = atomicExch(&head[cell], i);
    }
}

__global__ void emit_kernel(const float* __restrict__ feat,
                            const int* __restrict__ head,
                            const int* __restrict__ nxt,
                            float* __restrict__ out) {
    long long t  = (long long)blockIdx.x * blockDim.x + threadIdx.x; // < 33.5M
    long long o4 = t << 2;                       // base output element index
    int s4 = (int)(o4 & (S3 - 1));               // spatial pos (multiple of 4)
    int bc = (int)(o4 >> LOG_S3);                // b*C + c
    int c  = bc & (C_CH - 1);
    int b  = bc >> LOG_C;

    // 4 consecutive cells of batch b -> one coalesced int4 head load
    const int4 h4 = *(const int4*)(head + ((long long)b << LOG_S3) + s4);

    float4 v;
    int p; float acc;
    p = h4.x; acc = 0.f;
    while (p >= 0) { acc += feat[((long long)p << LOG_C) + c]; p = nxt[p]; }
    v.x = acc;
    p = h4.y; acc = 0.f;
    while (p >= 0) { acc += feat[((long long)p << LOG_C) + c]; p = nxt[p]; }
    v.y = acc;
    p = h4.z; acc = 0.f;
    while (p >= 0) { acc += feat[((long long)p << LOG_C) + c]; p = nxt[p]; }
    v.z = acc;
    p = h4.w; acc = 0.f;
    while (p >= 0) { acc += feat[((long long)p << LOG_C) + c]; p = nxt[p]; }
    v.w = acc;

    *(float4*)(out + o4) = v;
}

// ---------------- fallback path (only if d_ws were too small) ----------------
__global__ void zero_out_kernel(float4* __restrict__ out) {
    long long i = (long long)blockIdx.x * blockDim.x + threadIdx.x;
    out[i] = make_float4(0.f, 0.f, 0.f, 0.f);
}

__global__ void scatter_atomic_kernel(const float* __restrict__ feat,
                                      const int* __restrict__ idx,
                                      float* __restrict__ out, int n) {
    int i = blockIdx.x * blockDim.x + threadIdx.x;   // one thread per (n, c)
    int nn = i >> LOG_C;
    int c  = i & (C_CH - 1);
    if (nn < n) {
        int cell = idx[nn];
        int b = cell >> LOG_S3;
        int s = cell & (S3 - 1);
        long long o = (((long long)((b << LOG_C) + c)) << LOG_S3) + s;
        atomicAdd(&out[o], feat[i]);
    }
}

extern "C" void kernel_launch(void* const* d_in, const int* in_sizes, int n_in,
                              void* d_out, int out_size, void* d_ws, size_t ws_size,
                              hipStream_t stream) {
    const float* feat = (const float*)d_in[0];
    const int*   idx  = (const int*)d_in[1];
    float*       out  = (float*)d_out;
    const int N = in_sizes[1];                       // 262144 active sites

    const size_t head_bytes = (size_t)NCELL * sizeof(int);   // 8 MiB
    const size_t next_bytes = (size_t)N * sizeof(int);       // 1 MiB

    if (ws_size >= head_bytes + next_bytes) {
        int* head = (int*)d_ws;
        int* nxt  = (int*)((char*)d_ws + head_bytes);

        // Phase 1: head = -1 (d_ws is poisoned before every call)
        {
            int threads = NCELL / 4;                 // int4 stores
            init_head_kernel<<<threads / 256, 256, 0, stream>>>(head);
        }
        // Phase 2: build per-cell linked lists
        build_lists_kernel<<<(N + 255) / 256, 256, 0, stream>>>(idx, head, nxt, N);
        // Phase 3: streaming coalesced emit (zero-fill fused)
        {
            long long threads = OUT_ELEMS / 4;       // float4 stores
            emit_kernel<<<(int)(threads / 256), 256, 0, stream>>>(feat, head, nxt, out);
        }
    } else {
        // Fallback: memset + atomic scatter
        zero_out_kernel<<<(int)(OUT_ELEMS / 4 / 256), 256, 0, stream>>>((float4*)out);
        scatter_atomic_kernel<<<(N * C_CH) / 256, 256, 0, stream>>>(feat, idx, out, N);
    }
}

// Round 2
// 614.605 us; speedup vs baseline: 1.1313x; 1.1313x over previous
//
#include <hip/hip_runtime.h>

// SparseToDense: scatter [N, C] f32 features at flat (b,z,y,x) indices into
// dense [B, C, S, S, S] f32 output (channels-first).
// Fixed shape: N=262144, C=64, S=64, B=8. S^3=2^18, NCELL=2^21, out=512 MiB.
//
// Inverted-scatter structure:
//   Phase 1: head[cell] = -1                       (8 MiB in d_ws)
//   Phase 2: linked lists: nxt[n] = atomicExch(&head[idx[n]], n)
//   Phase 3: tile-emit. One block = 256 cells x 64 channels (64 KiB of out).
//     - thread t owns cell (s_base + t); reads head once into a register
//     - 4 chunks of 16 channels; per chunk: zero 16x256 LDS tile, walk the
//       (short, usually empty) list, load feat row chunk as 4x float4 (64 B,
//       one L1 line), accumulate into LDS column (no atomics: cell-owned)
//     - write out 16 channel rows, one wave per row, 1 KiB contiguous
//       nontemporal float4 stores.
//   => feat read EXACTLY once (64 MiB), head once (8 MiB), out written once
//      (512 MiB, coalesced). ~590 MiB total HBM traffic.

#define C_CH      64
#define LOG_C     6
#define LOG_S3    18
#define S3        (1 << LOG_S3)           // 262144 cells per batch
#define NCELL     (8 * S3)                // 2,097,152
#define OUT_ELEMS (8LL * C_CH * S3)       // 134,217,728 floats
#define TILE_S    256                     // cells per block
#define CHUNK_C   16                      // channels per LDS pass

__global__ void init_head_kernel(int* __restrict__ head) {
    int i = blockIdx.x * blockDim.x + threadIdx.x;   // NCELL/4 threads
    ((int4*)head)[i] = make_int4(-1, -1, -1, -1);
}

__global__ void build_lists_kernel(const int* __restrict__ idx,
                                   int* __restrict__ head,
                                   int* __restrict__ nxt, int n) {
    int i = blockIdx.x * blockDim.x + threadIdx.x;
    if (i < n) {
        int cell = idx[i];
        nxt[i] = atomicExch(&head[cell], i);
    }
}

__global__ void __launch_bounds__(256, 2)
emit_tile_kernel(const float* __restrict__ feat,
                 const int* __restrict__ head,
                 const int* __restrict__ nxt,
                 float* __restrict__ out) {
    __shared__ float tile[CHUNK_C * TILE_S];         // 16 KiB

    const int b      = blockIdx.x >> 10;             // S3/TILE_S = 1024 tiles/b
    const int s_base = (blockIdx.x & 1023) << 8;     // tile origin in spatial
    const int t      = threadIdx.x;

    // Register-cache the list head for this thread's cell (read once).
    const int h = head[((long long)b << LOG_S3) + s_base + t];

    const int lane = t & 63;
    const int wave = t >> 6;                         // 0..3

    #pragma unroll
    for (int chunk = 0; chunk < C_CH / CHUNK_C; ++chunk) {
        // ---- zero the LDS tile (1024 float4 / 256 threads) ----
        float4* t4 = (float4*)tile;
        #pragma unroll
        for (int k = 0; k < 4; ++k)
            t4[t + 256 * k] = make_float4(0.f, 0.f, 0.f, 0.f);
        __syncthreads();

        // ---- accumulate this cell's sites into column t of the tile ----
        int p = h;
        while (p >= 0) {
            const float4* fr = (const float4*)(feat + ((long long)p << LOG_C)
                                               + (chunk << 4));
            float4 f0 = fr[0], f1 = fr[1], f2 = fr[2], f3 = fr[3];
            float* col = tile + t;                   // stride TILE_S per chan
            col[0*TILE_S]  += f0.x;  col[1*TILE_S]  += f0.y;
            col[2*TILE_S]  += f0.z;  col[3*TILE_S]  += f0.w;
            col[4*TILE_S]  += f1.x;  col[5*TILE_S]  += f1.y;
            col[6*TILE_S]  += f1.z;  col[7*TILE_S]  += f1.w;
            col[8*TILE_S]  += f2.x;  col[9*TILE_S]  += f2.y;
            col[10*TILE_S] += f2.z;  col[11*TILE_S] += f2.w;
            col[12*TILE_S] += f3.x;  col[13*TILE_S] += f3.y;
            col[14*TILE_S] += f3.z;  col[15*TILE_S] += f3.w;
            p = nxt[p];
        }
        __syncthreads();

        // ---- stream the 16 channel rows out (wave per row, 4 rounds) ----
        #pragma unroll
        for (int r = 0; r < 4; ++r) {
            const int c = wave + (r << 2);           // 0..15 within chunk
            float4 v = *(float4*)(tile + c * TILE_S + (lane << 2));
            const int c_glob = (b << LOG_C) + (chunk << 4) + c;
            float4* dst = (float4*)(out + (((long long)c_glob) << LOG_S3)
                                    + s_base + (lane << 2));
            __builtin_nontemporal_store(v.x, &dst->x);
            __builtin_nontemporal_store(v.y, &dst->y);
            __builtin_nontemporal_store(v.z, &dst->z);
            __builtin_nontemporal_store(v.w, &dst->w);
        }
        __syncthreads();
    }
}

// ---------------- fallback path (only if d_ws were too small) ----------------
__global__ void zero_out_kernel(float4* __restrict__ out) {
    long long i = (long long)blockIdx.x * blockDim.x + threadIdx.x;
    out[i] = make_float4(0.f, 0.f, 0.f, 0.f);
}

__global__ void scatter_atomic_kernel(const float* __restrict__ feat,
                                      const int* __restrict__ idx,
                                      float* __restrict__ out, int n) {
    int i = blockIdx.x * blockDim.x + threadIdx.x;
    int nn = i >> LOG_C;
    int c  = i & (C_CH - 1);
    if (nn < n) {
        int cell = idx[nn];
        int b = cell >> LOG_S3;
        int s = cell & (S3 - 1);
        long long o = (((long long)((b << LOG_C) + c)) << LOG_S3) + s;
        atomicAdd(&out[o], feat[i]);
    }
}

extern "C" void kernel_launch(void* const* d_in, const int* in_sizes, int n_in,
                              void* d_out, int out_size, void* d_ws, size_t ws_size,
                              hipStream_t stream) {
    const float* feat = (const float*)d_in[0];
    const int*   idx  = (const int*)d_in[1];
    float*       out  = (float*)d_out;
    const int N = in_sizes[1];                       // 262144 active sites

    const size_t head_bytes = (size_t)NCELL * sizeof(int);   // 8 MiB
    const size_t next_bytes = (size_t)N * sizeof(int);       // 1 MiB

    if (ws_size >= head_bytes + next_bytes) {
        int* head = (int*)d_ws;
        int* nxt  = (int*)((char*)d_ws + head_bytes);

        init_head_kernel<<<NCELL / 4 / 256, 256, 0, stream>>>(head);
        build_lists_kernel<<<(N + 255) / 256, 256, 0, stream>>>(idx, head, nxt, N);
        emit_tile_kernel<<<NCELL / TILE_S, 256, 0, stream>>>(feat, head, nxt, out);
    } else {
        zero_out_kernel<<<(int)(OUT_ELEMS / 4 / 256), 256, 0, stream>>>((float4*)out);
        scatter_atomic_kernel<<<(N * C_CH) / 256, 256, 0, stream>>>(feat, idx, out, N);
    }
}